// Round 5
// baseline (199.274 us; speedup 1.0000x reference)
//
#include <hip/hip_runtime.h>
#include <cmath>

// Problem constants (from setup_inputs)
constexpr int B     = 32;
constexpr int L     = 2048;
constexpr int D_CTX = 512;
constexpr int D_Q   = 1024;
constexpr int H     = 256;
constexpr int PRUNE_L = -3;
constexpr int PRUNE_R = 3;
constexpr int W = PRUNE_R - PRUNE_L + 1;  // 7-position window
constexpr int KC = 16;                    // K-chunks for the query matmuls

// ---------------------------------------------------------------------------
// Kernel 1: K-split partials of BOTH query-side matmuls (float4 weight loads).
//   partQ[b,kc,j] = sum_{k in 64-chunk} q[k] * Wq[k,j]
//   part1[b,kc,j] = sum_{k in 64-chunk} q[k] * W1[D_CTX+k,j]
// grid = (KC, B) = 512 blocks, block = 256.
// Thread layout: jg = tid&63 (float4 of 4 cols, 16B/lane coalesced),
// sub = tid>>6 (4 sub-chunks of 16 k). 32 independent 16B loads per thread.
// ---------------------------------------------------------------------------
__global__ __launch_bounds__(256) void partial_kernel(
    const float* __restrict__ query,  // [B, D_Q]
    const float* __restrict__ Wq,     // [D_Q, H]
    const float* __restrict__ W1,     // [D_CTX+D_Q, H]
    float* __restrict__ partQ,        // [B, KC, H]
    float* __restrict__ part1)        // [B, KC, H]
{
    const int kc  = blockIdx.x;
    const int b   = blockIdx.y;
    const int tid = threadIdx.x;
    const int jg  = tid & 63;
    const int sub = tid >> 6;   // 0..3

    __shared__ float q_sh[64];
    if (tid < 64) q_sh[tid] = query[b * D_Q + kc * 64 + tid];
    __syncthreads();

    const float4* WqV = (const float4*)Wq;                       // [D_Q][64]
    const float4* W1V = (const float4*)(W1 + (size_t)D_CTX * H); // [D_Q][64]
    float4 aQ = make_float4(0.f, 0.f, 0.f, 0.f);
    float4 a1 = make_float4(0.f, 0.f, 0.f, 0.f);
    const int kbase = kc * 64 + sub * 16;
#pragma unroll
    for (int kk = 0; kk < 16; ++kk) {
        const int    k  = kbase + kk;
        const float  qk = q_sh[sub * 16 + kk];
        const float4 wq = WqV[(size_t)k * 64 + jg];
        const float4 w1 = W1V[(size_t)k * 64 + jg];
        aQ.x += qk * wq.x; aQ.y += qk * wq.y; aQ.z += qk * wq.z; aQ.w += qk * wq.w;
        a1.x += qk * w1.x; a1.y += qk * w1.y; a1.z += qk * w1.z; a1.w += qk * w1.w;
    }

    __shared__ float4 pq[4][64];
    __shared__ float4 p1[4][64];
    pq[sub][jg] = aQ;
    p1[sub][jg] = a1;
    __syncthreads();

    // float index within pq viewed flat: sub*256 + j  (j == tid)
    const float* pqf = (const float*)pq;
    const float* p1f = (const float*)p1;
    const float sQ = pqf[tid] + pqf[256 + tid] + pqf[512 + tid] + pqf[768 + tid];
    const float s1 = p1f[tid] + p1f[256 + tid] + p1f[512 + tid] + p1f[768 + tid];
    partQ[((size_t)b * KC + kc) * H + tid] = sQ;
    part1[((size_t)b * KC + kc) * H + tid] = s1;
}

// ---------------------------------------------------------------------------
// Kernel 2: fused stats + MLP score at the 7 window positions.
// Each (t,b) block redundantly reduces the b-row partials (identical fp
// sequence in all 7 blocks -> identical alpha/beta/kappa/center), then:
//   score = tanh(ctx_row @ W1[:D_CTX] + qpre) @ W2 + b2
//   post  = exp(score) * alpha * exp(-beta * (l-kappa)^2)
// grid = (W, B) = 224 blocks, block = 512.
// W1 fragment is register-prefetched before the partial reduce to overlap
// its cold-HBM latency with phase A.
// ---------------------------------------------------------------------------
__global__ __launch_bounds__(512) void score_kernel(
    const float* __restrict__ ctx,        // [B, L, D_CTX]
    const float* __restrict__ kappa_prev, // [B, 1]
    const float* __restrict__ bq,         // [H]
    const float* __restrict__ Ws,         // [H, 3]
    const float* __restrict__ bs,         // [3]
    const float* __restrict__ b1,         // [H]
    const float* __restrict__ W1,         // [D_CTX+D_Q, H]; rows [0, D_CTX)
    const float* __restrict__ W2,         // [H, 1]
    const float* __restrict__ b2,         // [1]
    const float* __restrict__ partQ,      // [B, KC, H]
    const float* __restrict__ part1,      // [B, KC, H]
    float* __restrict__ stats,            // [B, 4] = {alpha, beta, kappa, center}
    float* __restrict__ post)             // [B, W]
{
    const int t   = blockIdx.x;  // window slot 0..6
    const int b   = blockIdx.y;
    const int tid = threadIdx.x;
    const int jg  = tid & 63;
    const int kc8 = tid >> 6;    // 0..7
    const int k0  = kc8 * 64;

    // --- prefetch first 16 W1c rows of this thread's chunk (independent) ---
    const float4* Wv = (const float4*)W1;
    float4 wpre[16];
#pragma unroll
    for (int i = 0; i < 16; ++i) wpre[i] = Wv[(size_t)(k0 + i) * 64 + jg];

    // --- phase A: reduce partials -> qpre, h; compute stats ---------------
    __shared__ float qpre_sh[H];
    __shared__ float h_sh[H];
    __shared__ float s_sh[4];
    if (tid < H) {
        float s = 0.f;
#pragma unroll
        for (int kc = 0; kc < KC; ++kc) s += part1[((size_t)b * KC + kc) * H + tid];
        qpre_sh[tid] = s + b1[tid];
    } else {
        const int j = tid - H;
        float s = 0.f;
#pragma unroll
        for (int kc = 0; kc < KC; ++kc) s += partQ[((size_t)b * KC + kc) * H + j];
        h_sh[j] = tanhf(s + bq[j]);
    }
    __syncthreads();

    if (tid < 64) {
        float s0 = 0.f, s1 = 0.f, s2 = 0.f;
#pragma unroll
        for (int i = 0; i < 4; ++i) {
            const int   j  = tid + 64 * i;
            const float hv = h_sh[j];
            s0 += hv * Ws[j * 3 + 0];
            s1 += hv * Ws[j * 3 + 1];
            s2 += hv * Ws[j * 3 + 2];
        }
        for (int off = 32; off > 0; off >>= 1) {
            s0 += __shfl_down(s0, off);
            s1 += __shfl_down(s1, off);
            s2 += __shfl_down(s2, off);
        }
        if (tid == 0) {
            const float alpha  = expf(s0 + bs[0]);
            const float beta   = expf(s1 + bs[1]);
            const float kappa  = expf(s2 + bs[2]) + kappa_prev[b];
            const float center = rintf(kappa);  // round-half-even == jnp.round
            s_sh[0] = alpha; s_sh[1] = beta; s_sh[2] = kappa; s_sh[3] = center;
            // redundant identical-value writes from the 7 t-blocks: benign
            stats[b * 4 + 0] = alpha;
            stats[b * 4 + 1] = beta;
            stats[b * 4 + 2] = kappa;
            stats[b * 4 + 3] = center;
        }
    }
    __syncthreads();
    const float alpha  = s_sh[0];
    const float beta   = s_sh[1];
    const float kappa  = s_sh[2];
    const int   center = (int)s_sh[3];
    const int   l      = center + PRUNE_L + t;

    if (l < 0 || l >= L) {               // block-uniform branch
        if (tid == 0) post[b * W + t] = 0.0f;
        return;
    }

    // --- phase B: ctx-half matmul + score ---------------------------------
    __shared__ float  c_sh[D_CTX];       // 2 KB
    __shared__ float4 part[8][64];       // 8 KB
    __shared__ float  red[H];            // 1 KB

    const float4* ctx4 = (const float4*)(ctx + ((size_t)b * L + (size_t)l) * D_CTX);
    if (tid < D_CTX / 4) ((float4*)c_sh)[tid] = ctx4[tid];
    __syncthreads();

    float4 acc = make_float4(0.f, 0.f, 0.f, 0.f);
#pragma unroll
    for (int i = 0; i < 16; ++i) {       // prefetched rows
        const float  ck = c_sh[k0 + i];
        const float4 w  = wpre[i];
        acc.x += ck * w.x; acc.y += ck * w.y;
        acc.z += ck * w.z; acc.w += ck * w.w;
    }
#pragma unroll 8
    for (int k = k0 + 16; k < k0 + 64; ++k) {
        const float  ck = c_sh[k];
        const float4 w  = Wv[(size_t)k * 64 + jg];
        acc.x += ck * w.x; acc.y += ck * w.y;
        acc.z += ck * w.z; acc.w += ck * w.w;
    }
    part[kc8][jg] = acc;
    __syncthreads();
    for (int s = 4; s > 0; s >>= 1) {    // 8-way K-chunk reduce
        if (kc8 < s) {
            float4 a = part[kc8][jg], c = part[kc8 + s][jg];
            a.x += c.x; a.y += c.y; a.z += c.z; a.w += c.w;
            part[kc8][jg] = a;
        }
        __syncthreads();
    }
    if (tid < H) {
        const float pre = ((const float*)part)[tid] + qpre_sh[tid];
        red[tid] = tanhf(pre) * W2[tid];
    }
    __syncthreads();
    if (tid < 64) {
        float s = red[tid] + red[tid + 64] + red[tid + 128] + red[tid + 192];
        for (int off = 32; off > 0; off >>= 1) s += __shfl_down(s, off);
        if (tid == 0) {
            const float diff = (float)l - kappa;
            post[b * W + t] = expf(s + b2[0]) * alpha * expf(-beta * diff * diff);
        }
    }
}

// ---------------------------------------------------------------------------
// Kernel 3: normalize posterior, zero+scatter p_ctx, expected_ctx gather.
// grid = (8, B) = 256 blocks, block = 256. Each seg owns a 256-float slice of
// the p_ctx row (zeroes it, scatters any window entry landing inside it — no
// cross-block ordering hazard). Seg 0 also computes expected_ctx.
// ---------------------------------------------------------------------------
__global__ __launch_bounds__(256) void combine_kernel(
    const float* __restrict__ ctx,    // [B, L, D_CTX]
    const float* __restrict__ stats,  // [B, 4]
    const float* __restrict__ post,   // [B, W]
    float* __restrict__ out_e,        // [B, D_CTX]
    float* __restrict__ out_p)        // [B, L]
{
    const int seg = blockIdx.x;  // 0..7
    const int b   = blockIdx.y;
    const int tid = threadIdx.x;

    __shared__ float p_sh[W];
    __shared__ int   l_sh[W];
    if (tid == 0) {
        const int center = (int)stats[b * 4 + 3];
        float sum = 0.0f;
        for (int t = 0; t < W; ++t) sum += post[b * W + t];
        const float inv = 1.0f / sum;  // sum==0 -> NaN, same as reference
        for (int t = 0; t < W; ++t) {
            p_sh[t] = post[b * W + t] * inv;
            l_sh[t] = center + PRUNE_L + t;
        }
    }
    __syncthreads();

    // zero my 1 KB slice of the p_ctx row, then scatter entries inside it
    float4* prow = (float4*)(out_p + (size_t)b * L);
    if (tid < 64) prow[seg * 64 + tid] = make_float4(0.f, 0.f, 0.f, 0.f);
    __syncthreads();
    if (tid < W) {
        const int l = l_sh[tid];
        if (l >= seg * 256 && l < (seg + 1) * 256)   // implies 0 <= l < L
            out_p[(size_t)b * L + l] = p_sh[tid];
    }

    // expected_ctx: 7-term weighted float4 gather (seg 0 only)
    if (seg == 0 && tid < D_CTX / 4) {
        float4 acc = make_float4(0.f, 0.f, 0.f, 0.f);
#pragma unroll
        for (int t = 0; t < W; ++t) {
            const int l = l_sh[t];
            if (l >= 0 && l < L) {
                const float4 c = ((const float4*)(ctx + ((size_t)b * L + (size_t)l) * D_CTX))[tid];
                const float  p = p_sh[t];
                acc.x += p * c.x; acc.y += p * c.y;
                acc.z += p * c.z; acc.w += p * c.w;
            }
        }
        ((float4*)(out_e + (size_t)b * D_CTX))[tid] = acc;
    }
}

extern "C" void kernel_launch(void* const* d_in, const int* in_sizes, int n_in,
                              void* d_out, int out_size, void* d_ws, size_t ws_size,
                              hipStream_t stream) {
    const float* query      = (const float*)d_in[0];
    const float* ctx        = (const float*)d_in[1];
    const float* kappa_prev = (const float*)d_in[2];
    const float* Wq         = (const float*)d_in[3];
    const float* bq         = (const float*)d_in[4];
    const float* Ws         = (const float*)d_in[5];
    const float* bs         = (const float*)d_in[6];
    const float* W1         = (const float*)d_in[7];
    const float* b1         = (const float*)d_in[8];
    const float* W2         = (const float*)d_in[9];
    const float* b2         = (const float*)d_in[10];

    float* out   = (float*)d_out;
    float* out_e = out;              // [B, D_CTX]
    float* out_p = out + B * D_CTX;  // [B, L]

    // Workspace layout (ws base is 16B-aligned; offsets keep it that way):
    float* stats = (float*)d_ws;               // [B, 4]  = 128 floats
    float* post  = stats + B * 4;              // [B, W]  = 224 floats -> 352 total
    float* partQ = post + B * W;               // [B, KC, H]; 352*4 % 16 == 0
    float* part1 = partQ + (size_t)B * KC * H; // [B, KC, H]

    partial_kernel<<<dim3(KC, B), 256, 0, stream>>>(query, Wq, W1, partQ, part1);
    score_kernel<<<dim3(W, B), 512, 0, stream>>>(ctx, kappa_prev, bq, Ws, bs, b1,
                                                 W1, W2, b2, partQ, part1, stats, post);
    combine_kernel<<<dim3(8, B), 256, 0, stream>>>(ctx, stats, post, out_e, out_p);
}